// Round 1
// baseline (290.274 us; speedup 1.0000x reference)
//
#include <hip/hip_runtime.h>

// ---------- types ----------
typedef _Float16 f16x8 __attribute__((ext_vector_type(8)));
typedef _Float16 f16x4 __attribute__((ext_vector_type(4)));
typedef unsigned short u16x8 __attribute__((ext_vector_type(8)));
typedef unsigned short u16x4 __attribute__((ext_vector_type(4)));
typedef float f32x4 __attribute__((ext_vector_type(4)));

#define GLOAD_LDS16(GP, LP)                                                        \
  __builtin_amdgcn_global_load_lds((const __attribute__((address_space(1))) void*)(GP), \
                                   (__attribute__((address_space(3))) void*)(LP), 16, 0, 0)

__device__ __forceinline__ unsigned int pkh(float a, float b) {
  return __builtin_bit_cast(unsigned int, __builtin_amdgcn_cvt_pkrtz(a, b));
}
__device__ __forceinline__ f16x8 ldfragh(const unsigned short* p) {
  return __builtin_bit_cast(f16x8, *(const u16x8*)p);
}
__device__ __forceinline__ f16x4 ldfragh4(const unsigned short* p) {
  return __builtin_bit_cast(f16x4, *(const u16x4*)p);
}
__device__ __forceinline__ f32x4 mfma32h(f16x8 a, f16x8 b, f32x4 c) {
  return __builtin_amdgcn_mfma_f32_16x16x32_f16(a, b, c, 0, 0, 0);
}
__device__ __forceinline__ f32x4 mfma16h(f16x4 a, f16x4 b, f32x4 c) {
  return __builtin_amdgcn_mfma_f32_16x16x16f16(a, b, c, 0, 0, 0);
}

// ---------- problem constants ----------
// B=8 P=4 N=512 C=768 H=12 HD=64; M = B*P*N = 16384
#define MTOK   16384
#define CDIM   768
#define C3     2304
#define C2     1536
#define NX     12582912   // M*C
#define NQW    1769472    // 3C*C
#define NPW    589824     // C*C

#define QSCALE_LOG2E 0.1803368801111204f

// ws offsets (bytes)
#define XB_OFF    0ul
#define WQKV_OFF  25165824ul
#define WPROJ_OFF 28704768ul
#define QK_OFF    29884416ul
#define VT_OFF    80216064ul

// ---------- kernel 1: fp32 -> f16 convert (+ fold SCALE*log2e into Wq rows) ----------
__global__ __launch_bounds__(256) void convert_kernel(
    const float* __restrict__ x, const float* __restrict__ wqkv,
    const float* __restrict__ wproj, unsigned short* __restrict__ xb,
    unsigned short* __restrict__ wqkvb, unsigned short* __restrict__ wprojb) {
  const int NX4 = NX / 4, NQ4 = NQW / 4, NP4 = NPW / 4;
  const int total = NX4 + NQ4 + NP4;
  for (int i = blockIdx.x * 256 + threadIdx.x; i < total; i += gridDim.x * 256) {
    const float4* src; unsigned short* dst; float scale = 1.f; int j;
    if (i < NX4) { src = (const float4*)x; dst = xb; j = i; }
    else if (i < NX4 + NQ4) {
      j = i - NX4; src = (const float4*)wqkv; dst = wqkvb;
      int d = (j * 4) / CDIM; if (d < CDIM) scale = QSCALE_LOG2E;
    } else { j = i - NX4 - NQ4; src = (const float4*)wproj; dst = wprojb; }
    float4 v = src[j];
    uint2 pk; pk.x = pkh(v.x * scale, v.y * scale); pk.y = pkh(v.z * scale, v.w * scale);
    *(uint2*)(dst + (long)j * 4) = pk;
  }
}

// ---------- GEMM (B^T input), 256x256 tile, BK=32, ring-4 LDS, counted-vmcnt ----------
// R9: replace 2-barrier/K-step structure (vmcnt(0) drain each step -> MfmaUtil 26%)
// with T3+T4 phase pipeline: 512 thr = 8 waves (2M x 4N), per-wave 128x64 out,
// ring of 4 K-tile buffers (4 x (A 16KB + B 16KB) = 128 KiB LDS), 2 phases of
// 16 MFMA per K-tile, ONE half-tile (2 glds) staged per phase, 3 K-tiles ahead.
// vmcnt(8) once per K-tile (never 0 in steady state); tail 4, 0.
// Race-freedom: slot written at phase P was last READ at phase P-2; reads complete
// (lgkm before MFMA) before the barrier after P-2's MFMA; glds of P issues after it.
// Swizzle: chunk_phys = chunk ^ ((row>>2)&3), applied on pre-swizzled global src
// (glds dest stays linear) and on ds_read addr; 2-way bank aliasing max (free).
// MODE 0: NTN=9; bn<6 -> q/k swapped epilogue, bn>=6 -> V -> vT transpose store.
// MODE 2: NTN=3; proj, swapped, fp32 out + vec4 bias.
template <int MODE, int NTN>
__global__ __launch_bounds__(512, 2) void gemm256(
    const unsigned short* __restrict__ A, const unsigned short* __restrict__ B,
    unsigned short* __restrict__ out_hf, unsigned short* __restrict__ out_vT,
    float* __restrict__ out_f32, const float* __restrict__ bias) {
  constexpr int K = 768;
  constexpr int NKT = K / 32;   // 24 K-tiles
  __shared__ unsigned short As[4][256 * 32];
  __shared__ unsigned short Bs[4][256 * 32];
  const int tid = threadIdx.x;
  const int wave = tid >> 6, lane = tid & 63;
  const int wy = wave >> 2, wx = wave & 3;
  const int l15 = lane & 15, quad = lane >> 4;

  // XCD swizzle: xcd = gid&7 -> bm rows = xcd (mod 8); 9 (or 3) consecutive
  // blocks per XCD share one 384KB A-panel in that XCD's L2.
  const int gid = blockIdx.x;
  const int bn = (gid >> 3) % NTN;
  const int bm = ((gid >> 3) / NTN) * 8 + (gid & 7);
  const bool swap = (MODE == 2) || (bn < 6);

  f32x4 acc[8][4];
#pragma unroll
  for (int i = 0; i < 8; i++)
#pragma unroll
    for (int j = 0; j < 4; j++) acc[i][j] = f32x4{0.f, 0.f, 0.f, 0.f};

  const unsigned short* Ab = A + (long)bm * 256 * K;
  const unsigned short* Bb = B + (long)bn * 256 * K;

  // staging: unit = 16KB = 1024 chunks of 16B; thread covers chunks c0, c1.
  // LDS dest linear (glds constraint: uniform base + lane*16); global source
  // pre-swizzled so that LDS phys chunk p holds logical chunk p ^ ((row>>2)&3).
  const int c0 = wave * 128 + lane;
  const int c1 = c0 + 64;
  const int r0 = c0 >> 2, r1 = c1 >> 2;
  const long g0 = (long)r0 * K + (long)(((c0 & 3) ^ ((r0 >> 2) & 3)) * 8);
  const long g1 = (long)r1 * K + (long)(((c1 & 3) ^ ((r1 >> 2) & 3)) * 8);
  const int s0 = c0 * 8, s1 = c1 * 8;   // shorts

#define STAGE_A(kt) { GLOAD_LDS16(Ab + g0 + (kt) * 32, &As[(kt) & 3][s0]); \
                      GLOAD_LDS16(Ab + g1 + (kt) * 32, &As[(kt) & 3][s1]); }
#define STAGE_B(kt) { GLOAD_LDS16(Bb + g0 + (kt) * 32, &Bs[(kt) & 3][s0]); \
                      GLOAD_LDS16(Bb + g1 + (kt) * 32, &Bs[(kt) & 3][s1]); }

  // prologue: stage K-tiles 0,1,2 (12 glds); wait oldest 4 (A0,B0) landed.
  STAGE_A(0); STAGE_B(0); STAGE_A(1); STAGE_B(1); STAGE_A(2); STAGE_B(2);
  asm volatile("s_waitcnt vmcnt(8)" ::: "memory");
  __builtin_amdgcn_s_barrier();

  const int pho = (quad ^ (l15 >> 2)) * 8;   // swizzled k-chunk slot (shorts)
  const int arow = wy * 128 + l15;
  const int brow = wx * 64 + l15;

  for (int kt = 0; kt < NKT; kt++) {
    const unsigned short* Ac = As[kt & 3];
    const unsigned short* Bc = Bs[kt & 3];
    f16x8 af[4], bf[4];
    // ---------- phase 0: mt 0..3 (B frags live across both phases) ----------
#pragma unroll
    for (int nt = 0; nt < 4; nt++) bf[nt] = ldfragh(Bc + (brow + nt * 16) * 32 + pho);
#pragma unroll
    for (int mt = 0; mt < 4; mt++) af[mt] = ldfragh(Ac + (arow + mt * 16) * 32 + pho);
    if (kt < NKT - 3) STAGE_A(kt + 3);
    __builtin_amdgcn_s_barrier();
    asm volatile("s_waitcnt lgkmcnt(0)" ::: "memory");
    __builtin_amdgcn_s_setprio(1);
    if (swap) {
#pragma unroll
      for (int mt = 0; mt < 4; mt++)
#pragma unroll
        for (int nt = 0; nt < 4; nt++)
          acc[mt][nt] = mfma32h(bf[nt], af[mt], acc[mt][nt]);
    } else {
#pragma unroll
      for (int mt = 0; mt < 4; mt++)
#pragma unroll
        for (int nt = 0; nt < 4; nt++)
          acc[mt][nt] = mfma32h(af[mt], bf[nt], acc[mt][nt]);
    }
    __builtin_amdgcn_s_setprio(0);
    __builtin_amdgcn_s_barrier();
    // ---------- phase 1: mt 4..7 ----------
#pragma unroll
    for (int mt = 0; mt < 4; mt++) af[mt] = ldfragh(Ac + (arow + 64 + mt * 16) * 32 + pho);
    if (kt < NKT - 3) STAGE_B(kt + 3);
    // counted vmcnt: allow 4 units (kt+2, kt+3) in flight; forces kt+1 landed.
    if (kt < NKT - 3)       { asm volatile("s_waitcnt vmcnt(8)" ::: "memory"); }
    else if (kt == NKT - 3) { asm volatile("s_waitcnt vmcnt(4)" ::: "memory"); }
    else if (kt == NKT - 2) { asm volatile("s_waitcnt vmcnt(0)" ::: "memory"); }
    __builtin_amdgcn_s_barrier();
    asm volatile("s_waitcnt lgkmcnt(0)" ::: "memory");
    __builtin_amdgcn_s_setprio(1);
    if (swap) {
#pragma unroll
      for (int mt = 0; mt < 4; mt++)
#pragma unroll
        for (int nt = 0; nt < 4; nt++)
          acc[4 + mt][nt] = mfma32h(bf[nt], af[mt], acc[4 + mt][nt]);
    } else {
#pragma unroll
      for (int mt = 0; mt < 4; mt++)
#pragma unroll
        for (int nt = 0; nt < 4; nt++)
          acc[4 + mt][nt] = mfma32h(af[mt], bf[nt], acc[4 + mt][nt]);
    }
    __builtin_amdgcn_s_setprio(0);
    __builtin_amdgcn_s_barrier();
  }
#undef STAGE_A
#undef STAGE_B

  if (MODE == 0) {
    if (swap) {
      // q/k (bn 0..5): reg dim = d, l15 = m
#pragma unroll
      for (int mt = 0; mt < 8; mt++) {
        int m = bm * 256 + wy * 128 + mt * 16 + l15;
#pragma unroll
        for (int nt = 0; nt < 4; nt++) {
          int d0 = bn * 256 + wx * 64 + nt * 16 + quad * 4;
          uint2 pk; pk.x = pkh(acc[mt][nt][0], acc[mt][nt][1]);
          pk.y = pkh(acc[mt][nt][2], acc[mt][nt][3]);
          *(uint2*)(out_hf + (long)m * C2 + d0) = pk;
        }
      }
    } else {
      // V (bn 6..8): reg dim = m(token), l15 = d -> vT(bp,h,e,n)
#pragma unroll
      for (int mt = 0; mt < 8; mt++) {
        int mg = bm * 256 + wy * 128 + mt * 16 + quad * 4;
        int bp = mg >> 9, n0 = mg & 511;
#pragma unroll
        for (int nt = 0; nt < 4; nt++) {
          int dp = (bn - 6) * 256 + wx * 64 + nt * 16 + l15;   // 0..767
          int hh = dp >> 6, e = dp & 63;
          uint2 pk; pk.x = pkh(acc[mt][nt][0], acc[mt][nt][1]);
          pk.y = pkh(acc[mt][nt][2], acc[mt][nt][3]);
          *(uint2*)(out_vT + ((long)((bp * 12 + hh) * 64 + e) * 512 + n0)) = pk;
        }
      }
    }
  } else {
    // proj: swapped, fp32 out + vec4 bias
#pragma unroll
    for (int nt = 0; nt < 4; nt++) {
      int d0 = bn * 256 + wx * 64 + nt * 16 + quad * 4;
      float4 bv = *(const float4*)(bias + d0);
#pragma unroll
      for (int mt = 0; mt < 8; mt++) {
        int m = bm * 256 + wy * 128 + mt * 16 + l15;
        float4 o;
        o.x = acc[mt][nt][0] + bv.x; o.y = acc[mt][nt][1] + bv.y;
        o.z = acc[mt][nt][2] + bv.z; o.w = acc[mt][nt][3] + bv.w;
        *(float4*)(out_f32 + (long)m * CDIM + d0) = o;
      }
    }
  }
}

// ---------- kernel 3: flash attention (S^T form), 1 block = (head, 128 Q rows) ----------
__global__ __launch_bounds__(256, 4) void attn_kernel(
    const unsigned short* __restrict__ qk, const unsigned short* __restrict__ vT,
    unsigned short* __restrict__ aout) {
  const int bph = blockIdx.x;
  const int qt  = blockIdx.y;
  const int bp = bph / 12, h = bph % 12;
  const int tid = threadIdx.x;
  const int wave = tid >> 6, lane = tid & 63;
  const int l15 = lane & 15, quad = lane >> 4;

  __shared__ unsigned short Qs[128 * 72];
  __shared__ unsigned short Ks[64 * 72];
  __shared__ unsigned short Vs[64 * 72];

  const unsigned short* Qg = qk + (long)(bp * 512 + qt * 128) * C2 + h * 64;
  const unsigned short* Kg = qk + (long)(bp * 512) * C2 + CDIM + h * 64;
  const unsigned short* Vg = vT + (long)(bp * 12 + h) * 64 * 512;

  for (int i = 0; i < 4; i++) {
    int c = tid + i * 256;
    int row = c >> 3, c8 = c & 7;
    *(uint4*)(Qs + row * 72 + c8 * 8) = *(const uint4*)(Qg + (long)row * C2 + c8 * 8);
  }

  f32x4 o[2][4];
  float lrow[2] = {0.f, 0.f};
  for (int a = 0; a < 2; a++)
    for (int b = 0; b < 4; b++) o[a][b] = f32x4{0.f, 0.f, 0.f, 0.f};

  for (int ch = 0; ch < 8; ch++) {
    if (ch) __syncthreads();
    for (int i = 0; i < 2; i++) {
      int c = tid + i * 256;
      int row = c >> 3, c8 = c & 7;
      *(uint4*)(Ks + row * 72 + c8 * 8) = *(const uint4*)(Kg + (long)(ch * 64 + row) * C2 + c8 * 8);
      *(uint4*)(Vs + row * 72 + c8 * 8) = *(const uint4*)(Vg + (long)row * 512 + ch * 64 + c8 * 8);
    }
    __syncthreads();

    f32x4 st[2][4];
    for (int a = 0; a < 2; a++)
      for (int b = 0; b < 4; b++) st[a][b] = f32x4{0.f, 0.f, 0.f, 0.f};
    for (int ks = 0; ks < 2; ks++) {
      f16x8 qf[2];
      qf[0] = ldfragh(Qs + (wave * 32 +      l15) * 72 + ks * 32 + quad * 8);
      qf[1] = ldfragh(Qs + (wave * 32 + 16 + l15) * 72 + ks * 32 + quad * 8);
      for (int nt = 0; nt < 4; nt++) {
        f16x8 kf = ldfragh(Ks + (nt * 16 + l15) * 72 + ks * 32 + quad * 8);
        st[0][nt] = mfma32h(kf, qf[0], st[0][nt]);
        st[1][nt] = mfma32h(kf, qf[1], st[1][nt]);
      }
    }

    f16x4 pf[2][4];
    for (int mt2 = 0; mt2 < 2; mt2++) {
      float rs = 0.f;
      for (int nt = 0; nt < 4; nt++) {
        f32x4 p;
        for (int r = 0; r < 4; r++) {
          p[r] = __builtin_amdgcn_exp2f(st[mt2][nt][r]);
          rs += p[r];
        }
        uint2 pk2; pk2.x = pkh(p[0], p[1]); pk2.y = pkh(p[2], p[3]);
        pf[mt2][nt] = __builtin_bit_cast(f16x4, pk2);
      }
      lrow[mt2] += rs;
    }

    for (int nt = 0; nt < 4; nt++)
      for (int et = 0; et < 4; et++) {
        f16x4 vf = ldfragh4(Vs + (et * 16 + l15) * 72 + nt * 16 + quad * 4);
        o[0][et] = mfma16h(vf, pf[0][nt], o[0][et]);
        o[1][et] = mfma16h(vf, pf[1][nt], o[1][et]);
      }
  }

  for (int mt2 = 0; mt2 < 2; mt2++) {
    float l = lrow[mt2];
    l += __shfl_xor(l, 16);
    l += __shfl_xor(l, 32);
    float inv = 1.f / l;
    int q = qt * 128 + wave * 32 + mt2 * 16 + l15;
    for (int et = 0; et < 4; et++) {
      uint2 pk; pk.x = pkh(o[mt2][et][0] * inv, o[mt2][et][1] * inv);
      pk.y = pkh(o[mt2][et][2] * inv, o[mt2][et][3] * inv);
      *(uint2*)(aout + (long)(bp * 512 + q) * CDIM + h * 64 + et * 16 + quad * 4) = pk;
    }
  }
}

// ---------- launch ----------
extern "C" void kernel_launch(void* const* d_in, const int* in_sizes, int n_in,
                              void* d_out, int out_size, void* d_ws, size_t ws_size,
                              hipStream_t stream) {
  (void)in_sizes; (void)n_in; (void)out_size; (void)ws_size;
  const float* x     = (const float*)d_in[0];
  const float* wqkv  = (const float*)d_in[1];
  const float* wproj = (const float*)d_in[2];
  const float* bproj = (const float*)d_in[3];
  float* out = (float*)d_out;
  char* ws = (char*)d_ws;

  unsigned short* xb     = (unsigned short*)(ws + XB_OFF);
  unsigned short* wqkvb  = (unsigned short*)(ws + WQKV_OFF);
  unsigned short* wprojb = (unsigned short*)(ws + WPROJ_OFF);
  unsigned short* qkbuf  = (unsigned short*)(ws + QK_OFF);
  unsigned short* vTbuf  = (unsigned short*)(ws + VT_OFF);
  unsigned short* attn_o = xb;

  convert_kernel<<<2048, 256, 0, stream>>>(x, wqkv, wproj, xb, wqkvb, wprojb);
  // QKV: 64 x 9 = 576 blocks (576 % 8 == 0, swizzle bijective)
  gemm256<0, 9><<<576, 512, 0, stream>>>(xb, wqkvb, qkbuf, vTbuf, nullptr, nullptr);
  attn_kernel<<<dim3(384, 4), 256, 0, stream>>>(qkbuf, vTbuf, attn_o);
  // proj: 64 x 3 = 192 blocks
  gemm256<2, 3><<<192, 512, 0, stream>>>(attn_o, wprojb, nullptr, nullptr, out, bproj);
}

// Round 2
// 272.594 us; speedup vs baseline: 1.0649x; 1.0649x over previous
//
#include <hip/hip_runtime.h>

// ---------- types ----------
typedef _Float16 f16x8 __attribute__((ext_vector_type(8)));
typedef _Float16 f16x4 __attribute__((ext_vector_type(4)));
typedef unsigned short u16x8 __attribute__((ext_vector_type(8)));
typedef unsigned short u16x4 __attribute__((ext_vector_type(4)));
typedef float f32x4 __attribute__((ext_vector_type(4)));

#define GLOAD_LDS16(GP, LP)                                                        \
  __builtin_amdgcn_global_load_lds((const __attribute__((address_space(1))) void*)(GP), \
                                   (__attribute__((address_space(3))) void*)(LP), 16, 0, 0)

__device__ __forceinline__ unsigned int pkh(float a, float b) {
  return __builtin_bit_cast(unsigned int, __builtin_amdgcn_cvt_pkrtz(a, b));
}
__device__ __forceinline__ f16x8 ldfragh(const unsigned short* p) {
  return __builtin_bit_cast(f16x8, *(const u16x8*)p);
}
__device__ __forceinline__ f16x4 ldfragh4(const unsigned short* p) {
  return __builtin_bit_cast(f16x4, *(const u16x4*)p);
}
__device__ __forceinline__ f32x4 mfma32h(f16x8 a, f16x8 b, f32x4 c) {
  return __builtin_amdgcn_mfma_f32_16x16x32_f16(a, b, c, 0, 0, 0);
}
__device__ __forceinline__ f32x4 mfma16h(f16x4 a, f16x4 b, f32x4 c) {
  return __builtin_amdgcn_mfma_f32_16x16x16f16(a, b, c, 0, 0, 0);
}

// ---------- problem constants ----------
// B=8 P=4 N=512 C=768 H=12 HD=64; M = B*P*N = 16384
#define MTOK   16384
#define CDIM   768
#define C3     2304
#define C2     1536
#define NX     12582912   // M*C
#define NQW    1769472    // 3C*C
#define NPW    589824     // C*C

#define QSCALE_LOG2E 0.1803368801111204f

// ws offsets (bytes)
#define XB_OFF    0ul
#define WQKV_OFF  25165824ul
#define WPROJ_OFF 28704768ul
#define QK_OFF    29884416ul
#define VT_OFF    80216064ul

// ---------- kernel 1: fp32 -> f16 convert (+ fold SCALE*log2e into Wq rows) ----------
__global__ __launch_bounds__(256) void convert_kernel(
    const float* __restrict__ x, const float* __restrict__ wqkv,
    const float* __restrict__ wproj, unsigned short* __restrict__ xb,
    unsigned short* __restrict__ wqkvb, unsigned short* __restrict__ wprojb) {
  const int NX4 = NX / 4, NQ4 = NQW / 4, NP4 = NPW / 4;
  const int total = NX4 + NQ4 + NP4;
  for (int i = blockIdx.x * 256 + threadIdx.x; i < total; i += gridDim.x * 256) {
    const float4* src; unsigned short* dst; float scale = 1.f; int j;
    if (i < NX4) { src = (const float4*)x; dst = xb; j = i; }
    else if (i < NX4 + NQ4) {
      j = i - NX4; src = (const float4*)wqkv; dst = wqkvb;
      int d = (j * 4) / CDIM; if (d < CDIM) scale = QSCALE_LOG2E;
    } else { j = i - NX4 - NQ4; src = (const float4*)wproj; dst = wprojb; }
    float4 v = src[j];
    uint2 pk; pk.x = pkh(v.x * scale, v.y * scale); pk.y = pkh(v.z * scale, v.w * scale);
    *(uint2*)(dst + (long)j * 4) = pk;
  }
}

// ---------- GEMM (B^T input), 256x192 tile, BK=32, ring-4, counted-vmcnt ----------
// R2 post-mortem fixes vs R1 (19.6% MfmaUtil, 5.3M bank conflicts):
//  (a) conflict-free pair-interleaved LDS, NO swizzle: (row,q16B) at short-off
//      (row>>1)*64 + (row&1)*32 + q*8. A 16-row x 4-chunk fragment read is a
//      dense 1KiB block: banks = (row&1)*16 + q*4 + word = all 32, zero conflict.
//      glds dest linear; global src applies the inverse map (rule #21).
//  (b) ONE phase per K-tile: 11 ds_reads + stage(kt+3) + vmcnt + 1 barrier +
//      24-MFMA setprio cluster. 24 barriers total, no vmcnt(0) drain in loop.
//  (c) BN=192 -> QKV grid 768 = exactly 3 CU-rounds (was 576 = 2.25, 75% pack);
//      proj grid 256 = exactly 1 round. LDS 112KiB.
// Race-freedom (proven by R1 passing): slot (kt+3)&3 written at iter kt was last
// read at iter kt-1 before barrier(kt-1); vmcnt precedes each shared barrier so
// all waves' glds for slot kt+1 are landed when iter kt+1 reads it.
template <int MODE, int NTN>
__global__ __launch_bounds__(512, 2) void gemm192(
    const unsigned short* __restrict__ A, const unsigned short* __restrict__ B,
    unsigned short* __restrict__ out_hf, unsigned short* __restrict__ out_vT,
    float* __restrict__ out_f32, const float* __restrict__ bias) {
  constexpr int K = 768;
  constexpr int NKT = 24;                    // K / 32
  __shared__ unsigned short As[4][8192];     // 256 rows x 32 shorts, pair-interleaved
  __shared__ unsigned short Bs[4][6144];     // 192 rows x 32 shorts
  const int tid = threadIdx.x;
  const int wave = tid >> 6, lane = tid & 63;
  const int wy = wave >> 2, wx = wave & 3;   // 2M x 4N waves; per-wave 128x48
  const int l15 = lane & 15, quad = lane >> 4;

  // XCD swizzle: gid&7 = xcd; blocks on one XCD share bm (A-panel in its L2).
  const int gid = blockIdx.x;
  const int bn = (gid >> 3) % NTN;
  const int bm = ((gid >> 3) / NTN) * 8 + (gid & 7);
  const bool swap = (MODE == 2) || (bn < 8);   // q/k cols: bn*192 < 1536 <=> bn<8

  f32x4 acc[8][3];
#pragma unroll
  for (int i = 0; i < 8; i++)
#pragma unroll
    for (int j = 0; j < 3; j++) acc[i][j] = f32x4{0.f, 0.f, 0.f, 0.f};

  const unsigned short* Ab = A + (long)bm * 256 * K;
  const unsigned short* Bb = B + (long)bn * 192 * K;

  // staging: phys chunk c (16B) -> logical row = 2*(c>>3) + ((c>>2)&1), q = c&3.
  // A: 1024 chunks (2/thread). B: 768 chunks (1/thread + 1 extra for tid<256).
  const int cA0 = tid, cA1 = tid + 512;
  const int cB0 = tid, cB1 = tid + 512;
  const bool extraB = (tid < 256);
  const long gA0 = (long)(2 * (cA0 >> 3) + ((cA0 >> 2) & 1)) * K + (cA0 & 3) * 8;
  const long gA1 = (long)(2 * (cA1 >> 3) + ((cA1 >> 2) & 1)) * K + (cA1 & 3) * 8;
  const long gB0 = (long)(2 * (cB0 >> 3) + ((cB0 >> 2) & 1)) * K + (cB0 & 3) * 8;
  const long gB1 = (long)(2 * (cB1 >> 3) + ((cB1 >> 2) & 1)) * K + (cB1 & 3) * 8;
  const int sA0 = cA0 * 8, sA1 = cA1 * 8, sB0 = cB0 * 8, sB1 = cB1 * 8;

#define STAGE(kt) { const long kk = (long)(kt) * 32; const int sl = (kt) & 3;      \
    GLOAD_LDS16(Ab + gA0 + kk, &As[sl][sA0]);                                      \
    GLOAD_LDS16(Ab + gA1 + kk, &As[sl][sA1]);                                      \
    GLOAD_LDS16(Bb + gB0 + kk, &Bs[sl][sB0]);                                      \
    if (extraB) GLOAD_LDS16(Bb + gB1 + kk, &Bs[sl][sB1]); }

  // prologue: stage K-tiles 0,1,2; guarantee kt0 landed (allow kt1,kt2 in flight).
  STAGE(0); STAGE(1); STAGE(2);
  if (wave < 4) { asm volatile("s_waitcnt vmcnt(8)" ::: "memory"); }
  else          { asm volatile("s_waitcnt vmcnt(6)" ::: "memory"); }
  __builtin_amdgcn_s_barrier();
  asm volatile("" ::: "memory");

  // per-thread fragment read offset inside the pair-interleaved layout
  const int rl = (l15 >> 1) * 64 + (l15 & 1) * 32 + quad * 8;
  const int aoff = wy * 4096;     // (wy*128)>>1 * 64
  const int boff = wx * 1536;     // (wx*48)>>1 * 64

  for (int kt = 0; kt < NKT; kt++) {
    const unsigned short* Ac = As[kt & 3];
    const unsigned short* Bc = Bs[kt & 3];
    f16x8 af[8], bf[3];
#pragma unroll
    for (int mt = 0; mt < 8; mt++) af[mt] = ldfragh(Ac + aoff + mt * 512 + rl);
#pragma unroll
    for (int nt = 0; nt < 3; nt++) bf[nt] = ldfragh(Bc + boff + nt * 512 + rl);

    if (kt < NKT - 3) {
      STAGE(kt + 3);
      // steady: outstanding = kt+1,kt+2,kt+3 units; drain own kt+1 units.
      if (wave < 4) { asm volatile("s_waitcnt vmcnt(8)" ::: "memory"); }
      else          { asm volatile("s_waitcnt vmcnt(6)" ::: "memory"); }
    } else if (kt == NKT - 3) {
      if (wave < 4) { asm volatile("s_waitcnt vmcnt(4)" ::: "memory"); }
      else          { asm volatile("s_waitcnt vmcnt(3)" ::: "memory"); }
    } else if (kt == NKT - 2) {
      asm volatile("s_waitcnt vmcnt(0)" ::: "memory");
    }
    __builtin_amdgcn_s_barrier();
    asm volatile("" ::: "memory");

    __builtin_amdgcn_s_setprio(1);
    if (swap) {
#pragma unroll
      for (int mt = 0; mt < 8; mt++)
#pragma unroll
        for (int nt = 0; nt < 3; nt++)
          acc[mt][nt] = mfma32h(bf[nt], af[mt], acc[mt][nt]);
    } else {
#pragma unroll
      for (int mt = 0; mt < 8; mt++)
#pragma unroll
        for (int nt = 0; nt < 3; nt++)
          acc[mt][nt] = mfma32h(af[mt], bf[nt], acc[mt][nt]);
    }
    __builtin_amdgcn_s_setprio(0);
  }
#undef STAGE

  if (MODE == 0) {
    if (swap) {
      // q/k (bn 0..7): reg dim = d, l15 = m
#pragma unroll
      for (int mt = 0; mt < 8; mt++) {
        int m = bm * 256 + wy * 128 + mt * 16 + l15;
#pragma unroll
        for (int nt = 0; nt < 3; nt++) {
          int d0 = bn * 192 + wx * 48 + nt * 16 + quad * 4;
          uint2 pk; pk.x = pkh(acc[mt][nt][0], acc[mt][nt][1]);
          pk.y = pkh(acc[mt][nt][2], acc[mt][nt][3]);
          *(uint2*)(out_hf + (long)m * C2 + d0) = pk;
        }
      }
    } else {
      // V (bn 8..11): reg dim = m(token), l15 = d -> vT(bp,h,e,n)
#pragma unroll
      for (int mt = 0; mt < 8; mt++) {
        int mg = bm * 256 + wy * 128 + mt * 16 + quad * 4;
        int bp = mg >> 9, n0 = mg & 511;
#pragma unroll
        for (int nt = 0; nt < 3; nt++) {
          int dp = (bn - 8) * 192 + wx * 48 + nt * 16 + l15;   // 0..767
          int hh = dp >> 6, e = dp & 63;
          uint2 pk; pk.x = pkh(acc[mt][nt][0], acc[mt][nt][1]);
          pk.y = pkh(acc[mt][nt][2], acc[mt][nt][3]);
          *(uint2*)(out_vT + ((long)((bp * 12 + hh) * 64 + e) * 512 + n0)) = pk;
        }
      }
    }
  } else {
    // proj: swapped, fp32 out + vec4 bias
#pragma unroll
    for (int nt = 0; nt < 3; nt++) {
      int d0 = bn * 192 + wx * 48 + nt * 16 + quad * 4;
      float4 bv = *(const float4*)(bias + d0);
#pragma unroll
      for (int mt = 0; mt < 8; mt++) {
        int m = bm * 256 + wy * 128 + mt * 16 + l15;
        float4 o;
        o.x = acc[mt][nt][0] + bv.x; o.y = acc[mt][nt][1] + bv.y;
        o.z = acc[mt][nt][2] + bv.z; o.w = acc[mt][nt][3] + bv.w;
        *(float4*)(out_f32 + (long)m * CDIM + d0) = o;
      }
    }
  }
}

// ---------- kernel 3: flash attention (S^T form), 1 block = (head, 128 Q rows) ----------
__global__ __launch_bounds__(256, 4) void attn_kernel(
    const unsigned short* __restrict__ qk, const unsigned short* __restrict__ vT,
    unsigned short* __restrict__ aout) {
  const int bph = blockIdx.x;
  const int qt  = blockIdx.y;
  const int bp = bph / 12, h = bph % 12;
  const int tid = threadIdx.x;
  const int wave = tid >> 6, lane = tid & 63;
  const int l15 = lane & 15, quad = lane >> 4;

  __shared__ unsigned short Qs[128 * 72];
  __shared__ unsigned short Ks[64 * 72];
  __shared__ unsigned short Vs[64 * 72];

  const unsigned short* Qg = qk + (long)(bp * 512 + qt * 128) * C2 + h * 64;
  const unsigned short* Kg = qk + (long)(bp * 512) * C2 + CDIM + h * 64;
  const unsigned short* Vg = vT + (long)(bp * 12 + h) * 64 * 512;

  for (int i = 0; i < 4; i++) {
    int c = tid + i * 256;
    int row = c >> 3, c8 = c & 7;
    *(uint4*)(Qs + row * 72 + c8 * 8) = *(const uint4*)(Qg + (long)row * C2 + c8 * 8);
  }

  f32x4 o[2][4];
  float lrow[2] = {0.f, 0.f};
  for (int a = 0; a < 2; a++)
    for (int b = 0; b < 4; b++) o[a][b] = f32x4{0.f, 0.f, 0.f, 0.f};

  for (int ch = 0; ch < 8; ch++) {
    if (ch) __syncthreads();
    for (int i = 0; i < 2; i++) {
      int c = tid + i * 256;
      int row = c >> 3, c8 = c & 7;
      *(uint4*)(Ks + row * 72 + c8 * 8) = *(const uint4*)(Kg + (long)(ch * 64 + row) * C2 + c8 * 8);
      *(uint4*)(Vs + row * 72 + c8 * 8) = *(const uint4*)(Vg + (long)row * 512 + ch * 64 + c8 * 8);
    }
    __syncthreads();

    f32x4 st[2][4];
    for (int a = 0; a < 2; a++)
      for (int b = 0; b < 4; b++) st[a][b] = f32x4{0.f, 0.f, 0.f, 0.f};
    for (int ks = 0; ks < 2; ks++) {
      f16x8 qf[2];
      qf[0] = ldfragh(Qs + (wave * 32 +      l15) * 72 + ks * 32 + quad * 8);
      qf[1] = ldfragh(Qs + (wave * 32 + 16 + l15) * 72 + ks * 32 + quad * 8);
      for (int nt = 0; nt < 4; nt++) {
        f16x8 kf = ldfragh(Ks + (nt * 16 + l15) * 72 + ks * 32 + quad * 8);
        st[0][nt] = mfma32h(kf, qf[0], st[0][nt]);
        st[1][nt] = mfma32h(kf, qf[1], st[1][nt]);
      }
    }

    f16x4 pf[2][4];
    for (int mt2 = 0; mt2 < 2; mt2++) {
      float rs = 0.f;
      for (int nt = 0; nt < 4; nt++) {
        f32x4 p;
        for (int r = 0; r < 4; r++) {
          p[r] = __builtin_amdgcn_exp2f(st[mt2][nt][r]);
          rs += p[r];
        }
        uint2 pk2; pk2.x = pkh(p[0], p[1]); pk2.y = pkh(p[2], p[3]);
        pf[mt2][nt] = __builtin_bit_cast(f16x4, pk2);
      }
      lrow[mt2] += rs;
    }

    for (int nt = 0; nt < 4; nt++)
      for (int et = 0; et < 4; et++) {
        f16x4 vf = ldfragh4(Vs + (et * 16 + l15) * 72 + nt * 16 + quad * 4);
        o[0][et] = mfma16h(vf, pf[0][nt], o[0][et]);
        o[1][et] = mfma16h(vf, pf[1][nt], o[1][et]);
      }
  }

  for (int mt2 = 0; mt2 < 2; mt2++) {
    float l = lrow[mt2];
    l += __shfl_xor(l, 16);
    l += __shfl_xor(l, 32);
    float inv = 1.f / l;
    int q = qt * 128 + wave * 32 + mt2 * 16 + l15;
    for (int et = 0; et < 4; et++) {
      uint2 pk; pk.x = pkh(o[mt2][et][0] * inv, o[mt2][et][1] * inv);
      pk.y = pkh(o[mt2][et][2] * inv, o[mt2][et][3] * inv);
      *(uint2*)(aout + (long)(bp * 512 + q) * CDIM + h * 64 + et * 16 + quad * 4) = pk;
    }
  }
}

// ---------- launch ----------
extern "C" void kernel_launch(void* const* d_in, const int* in_sizes, int n_in,
                              void* d_out, int out_size, void* d_ws, size_t ws_size,
                              hipStream_t stream) {
  (void)in_sizes; (void)n_in; (void)out_size; (void)ws_size;
  const float* x     = (const float*)d_in[0];
  const float* wqkv  = (const float*)d_in[1];
  const float* wproj = (const float*)d_in[2];
  const float* bproj = (const float*)d_in[3];
  float* out = (float*)d_out;
  char* ws = (char*)d_ws;

  unsigned short* xb     = (unsigned short*)(ws + XB_OFF);
  unsigned short* wqkvb  = (unsigned short*)(ws + WQKV_OFF);
  unsigned short* wprojb = (unsigned short*)(ws + WPROJ_OFF);
  unsigned short* qkbuf  = (unsigned short*)(ws + QK_OFF);
  unsigned short* vTbuf  = (unsigned short*)(ws + VT_OFF);
  unsigned short* attn_o = xb;

  convert_kernel<<<2048, 256, 0, stream>>>(x, wqkv, wproj, xb, wqkvb, wprojb);
  // QKV: 64 m-tiles x 12 n-tiles = 768 blocks = exactly 3 rounds of 256 CUs
  gemm192<0, 12><<<768, 512, 0, stream>>>(xb, wqkvb, qkbuf, vTbuf, nullptr, nullptr);
  attn_kernel<<<dim3(384, 4), 256, 0, stream>>>(qkbuf, vTbuf, attn_o);
  // proj: 64 x 4 = 256 blocks = exactly 1 round
  gemm192<2, 4><<<256, 512, 0, stream>>>(attn_o, wprojb, nullptr, nullptr, out, bproj);
}